// Round 6
// baseline (151.202 us; speedup 1.0000x reference)
//
#include <hip/hip_runtime.h>

#define Bn 8
#define Ln 256
#define Dn 128
#define Hn 6
#define En 32
#define WXROW (Hn + 2*Dn + En)   // 294

// -------- Kernel 1: T partials --------
// grid = b(8) x itile(8, 32 rows) x jq(4, 64 js) = 256 blocks, 512 threads
// T[jq][b,i,d] = sum_{j in quarter} adj_avg[b,i,j] * x[b,j,d]
__global__ __launch_bounds__(512) void kT(
    const float* __restrict__ wadj, const float* __restrict__ x,
    float* __restrict__ T)
{
    __shared__ float adj_s[32][68];   // 8.7 KB, pad 68: bank=(4i+j)%32, 2-way max
    __shared__ float x_s[32][128];    // 16 KB

    const int t   = threadIdx.x;
    const int blk = blockIdx.x;
    const int jq  = blk & 3;
    const int it  = (blk >> 2) & 7;
    const int b   = blk >> 5;
    const int i0  = it * 32;

    // adj_s[row][jl] = mean_h wadj[b,h,i0+row, jq*64+jl]  (32 rows x 16 float4)
    {
        const int row = t >> 4, j4 = t & 15;
        const float4* w4 = (const float4*)wadj;
        float4 s = {0.f, 0.f, 0.f, 0.f};
        #pragma unroll
        for (int h = 0; h < Hn; ++h) {
            const float4 v = w4[(((size_t)b * Hn + h) * Ln + i0 + row) * 64 + jq * 16 + j4];
            s.x += v.x; s.y += v.y; s.z += v.z; s.w += v.w;
        }
        const float inv_h = 1.0f / 6.0f;
        s.x *= inv_h; s.y *= inv_h; s.z *= inv_h; s.w *= inv_h;
        *(float4*)&adj_s[row][j4 * 4] = s;   // 272B row stride: 16B-aligned
    }
    __syncthreads();

    const int i  = t & 31;        // i-row within tile
    const int dg = t >> 5;        // d-group: d = dg*8 .. +8
    float acc[8] = {0.f, 0.f, 0.f, 0.f, 0.f, 0.f, 0.f, 0.f};

    #pragma unroll
    for (int ch = 0; ch < 2; ++ch) {
        // stage x[b, jq*64+ch*32 + (0..32), 0..128] -> x_s, coalesced
        #pragma unroll
        for (int rep = 0; rep < 2; ++rep) {
            const int idx = t + rep * 512;
            const int jj = idx >> 5, d4 = idx & 31;
            ((float4*)&x_s[jj][0])[d4] =
                ((const float4*)(x + ((size_t)b * Ln + jq * 64 + ch * 32 + jj) * Dn))[d4];
        }
        __syncthreads();
        #pragma unroll 4
        for (int jj = 0; jj < 32; ++jj) {
            const float a = adj_s[i][ch * 32 + jj];
            const float4 xv0 = *(const float4*)&x_s[jj][dg * 8];
            const float4 xv1 = *(const float4*)&x_s[jj][dg * 8 + 4];
            acc[0] = fmaf(a, xv0.x, acc[0]);
            acc[1] = fmaf(a, xv0.y, acc[1]);
            acc[2] = fmaf(a, xv0.z, acc[2]);
            acc[3] = fmaf(a, xv0.w, acc[3]);
            acc[4] = fmaf(a, xv1.x, acc[4]);
            acc[5] = fmaf(a, xv1.y, acc[5]);
            acc[6] = fmaf(a, xv1.z, acc[6]);
            acc[7] = fmaf(a, xv1.w, acc[7]);
        }
        __syncthreads();
    }

    float* Tq = T + (size_t)jq * (Bn * Ln * Dn);
    float4 s0 = {acc[0], acc[1], acc[2], acc[3]};
    float4 s1 = {acc[4], acc[5], acc[6], acc[7]};
    float* dst = &Tq[((size_t)b * Ln + i0 + i) * Dn + dg * 8];
    *(float4*)dst = s0;
    *(float4*)(dst + 4) = s1;
}

// -------- Kernel 2: G, out, n1/n2 --------
// grid = B * (L/4) = 512 blocks, 256 threads
__global__ __launch_bounds__(256) void kG(
    const float* __restrict__ T,
    const float* __restrict__ W_w, const float* __restrict__ W_b,
    const float* __restrict__ Wx_w,
    const float* __restrict__ Wxx_w, const float* __restrict__ Wxx_b,
    float* __restrict__ out, float* __restrict__ n1_ws, float* __restrict__ n2_ws)
{
    __shared__ float t_s[4][Dn];   // 2 KB
    __shared__ float g_s[4][Dn];   // 2 KB

    const int t  = threadIdx.x;
    const int b  = blockIdx.x >> 6;
    const int i0 = (blockIdx.x & 63) * 4;
    const size_t NT = (size_t)Bn * Ln * Dn;

    // sum the 4 partials
    #pragma unroll
    for (int rep = 0; rep < 2; ++rep) {
        const int idx = t + rep * 256;
        const int r = idx >> 7, d = idx & 127;
        const size_t g = ((size_t)b * Ln + i0 + r) * Dn + d;
        t_s[r][d] = T[g] + T[NT + g] + T[2 * NT + g] + T[3 * NT + g];
    }
    __syncthreads();

    // g[r][d] = relu(sum_c t_s[r][c]*W_w[d,c] + W_b[d]) for r in {s, s+2}
    {
        const int s = t >> 7, d = t & 127;
        const int r0 = s, r1 = s + 2;
        float a0 = W_b[d], a1 = a0;
        const float4* wr = (const float4*)(W_w + (size_t)d * Dn);
        const float4* t0 = (const float4*)&t_s[r0][0];
        const float4* t1 = (const float4*)&t_s[r1][0];
        #pragma unroll 8
        for (int c4 = 0; c4 < Dn / 4; ++c4) {
            const float4 w = wr[c4];
            const float4 u0 = t0[c4];
            const float4 u1 = t1[c4];
            a0 = fmaf(u0.x, w.x, a0); a0 = fmaf(u0.y, w.y, a0);
            a0 = fmaf(u0.z, w.z, a0); a0 = fmaf(u0.w, w.w, a0);
            a1 = fmaf(u1.x, w.x, a1); a1 = fmaf(u1.y, w.y, a1);
            a1 = fmaf(u1.z, w.z, a1); a1 = fmaf(u1.w, w.w, a1);
        }
        g_s[r0][d] = fmaxf(a0, 0.f);
        g_s[r1][d] = fmaxf(a1, 0.f);
    }
    __syncthreads();

    // out[b,i0+r,d] = sum_c g_s[r][c]*Wxx_w[d,c] + Wxx_b[d] for r in {s, s+2}
    {
        const int s = t >> 7, d = t & 127;
        const int r0 = s, r1 = s + 2;
        float a0 = Wxx_b[d], a1 = a0;
        const float4* wr = (const float4*)(Wxx_w + (size_t)d * Dn);
        const float4* g0 = (const float4*)&g_s[r0][0];
        const float4* g1 = (const float4*)&g_s[r1][0];
        #pragma unroll 8
        for (int c4 = 0; c4 < Dn / 4; ++c4) {
            const float4 w = wr[c4];
            const float4 u0 = g0[c4];
            const float4 u1 = g1[c4];
            a0 = fmaf(u0.x, w.x, a0); a0 = fmaf(u0.y, w.y, a0);
            a0 = fmaf(u0.z, w.z, a0); a0 = fmaf(u0.w, w.w, a0);
            a1 = fmaf(u1.x, w.x, a1); a1 = fmaf(u1.y, w.y, a1);
            a1 = fmaf(u1.z, w.z, a1); a1 = fmaf(u1.w, w.w, a1);
        }
        out[((size_t)b * Ln + (i0 + r0)) * Dn + d] = a0;
        out[((size_t)b * Ln + (i0 + r1)) * Dn + d] = a1;
    }

    // n1/n2: 48 dot-products of length 128
    if (t < 4 * 2 * Hn) {
        const int r  = t / (2 * Hn);
        const int kk = t % (2 * Hn);
        const int k  = (kk < Hn) ? kk : (kk - Hn);
        const bool isn2 = (kk >= Hn);
        const float* wrow = Wx_w + (size_t)k * WXROW + Hn + (isn2 ? Dn : 0);
        float acc = 0.f;
        #pragma unroll 8
        for (int c = 0; c < Dn; ++c)
            acc = fmaf(g_s[r][c], wrow[c], acc);
        const size_t idx = ((size_t)b * Hn + k) * Ln + (i0 + r);
        if (isn2) n2_ws[idx] = acc;
        else      n1_ws[idx] = acc;
    }
}

// -------- Kernel 3: new_adj (round-4 proven version) --------
// grid = B*L blocks (b,i), 256 threads (j)
#define EPAD 33
__global__ __launch_bounds__(256) void k_adj(
    const float* __restrict__ wadj, const float* __restrict__ e,
    const float* __restrict__ Wx_w, const float* __restrict__ Wx_b,
    const float* __restrict__ n1_ws, const float* __restrict__ n2_ws,
    float* __restrict__ new_adj)
{
    __shared__ float e_lds[Ln * EPAD];   // 33 KB, padded stride 33
    __shared__ float Wa_s[Hn][Hn];
    __shared__ float We_s[Hn][En];
    __shared__ float bias_n1[Hn];

    const int t = threadIdx.x;
    const int b = blockIdx.x >> 8;
    const int i = blockIdx.x & 255;

    if (t < Hn * Hn) {
        const int k = t / Hn, h = t % Hn;
        Wa_s[k][h] = Wx_w[(size_t)k * WXROW + h];
    }
    if (t >= 64 && t < 64 + Hn * En) {
        const int q = t - 64, k = q / En, c = q % En;
        We_s[k][c] = Wx_w[(size_t)k * WXROW + Hn + 2 * Dn + c];
    }
    if (t >= 32 && t < 32 + Hn) {
        const int k = t - 32;
        bias_n1[k] = Wx_b[k] + n1_ws[((size_t)b * Hn + k) * Ln + i];
    }

    // stage e[b,i,:,:] (256x32 floats = 32 KB) coalesced into padded LDS
    {
        const float4* ep4 = (const float4*)(e + (((size_t)b * Ln + i) * Ln) * En);
        #pragma unroll
        for (int k = 0; k < 8; ++k) {
            const int idx = t + k * 256;       // float4 index
            const float4 v = ep4[idx];
            const int j = idx >> 3;
            const int c = (idx & 7) * 4;
            float* dst = &e_lds[j * EPAD + c];
            dst[0] = v.x; dst[1] = v.y; dst[2] = v.z; dst[3] = v.w;
        }
    }
    __syncthreads();

    const int j = t;

    float ev[En];
    {
        const float* src = &e_lds[j * EPAD];
        #pragma unroll
        for (int c = 0; c < En; ++c) ev[c] = src[c];
    }

    float wv[Hn];
    #pragma unroll
    for (int h = 0; h < Hn; ++h)
        wv[h] = wadj[(((size_t)b * Hn + h) * Ln + i) * Ln + j];

    float n2v[Hn];
    #pragma unroll
    for (int k = 0; k < Hn; ++k)
        n2v[k] = n2_ws[((size_t)b * Hn + k) * Ln + j];

    #pragma unroll
    for (int k = 0; k < Hn; ++k) {
        float acc = bias_n1[k] + n2v[k];
        #pragma unroll
        for (int h = 0; h < Hn; ++h)
            acc = fmaf(wv[h], Wa_s[k][h], acc);
        #pragma unroll
        for (int c = 0; c < En; ++c)
            acc = fmaf(ev[c], We_s[k][c], acc);
        new_adj[(((size_t)b * Hn + k) * Ln + i) * Ln + j] = acc;
    }
}

extern "C" void kernel_launch(void* const* d_in, const int* in_sizes, int n_in,
                              void* d_out, int out_size, void* d_ws, size_t ws_size,
                              hipStream_t stream) {
    const float* x      = (const float*)d_in[0];
    const float* wadj   = (const float*)d_in[1];
    const float* e      = (const float*)d_in[2];
    const float* W_w    = (const float*)d_in[3];
    const float* W_b    = (const float*)d_in[4];
    const float* Wx_w   = (const float*)d_in[5];
    const float* Wx_b   = (const float*)d_in[6];
    const float* Wxx_w  = (const float*)d_in[7];
    const float* Wxx_b  = (const float*)d_in[8];

    float* out      = (float*)d_out;                   // (B,L,D)
    float* new_adj  = out + (size_t)Bn * Ln * Dn;      // (B,H,L,L)

    float* n1_ws = (float*)d_ws;                          // (B,H,L)
    float* n2_ws = n1_ws + (size_t)Bn * Hn * Ln;          // (B,H,L)
    float* T     = n2_ws + (size_t)Bn * Hn * Ln;          // 4 x (B,L,D) partials

    kT<<<256, 512, 0, stream>>>(wadj, x, T);
    kG<<<512, 256, 0, stream>>>(T, W_w, W_b, Wx_w, Wxx_w, Wxx_b,
                                out, n1_ws, n2_ws);
    k_adj<<<Bn * Ln, 256, 0, stream>>>(wadj, e, Wx_w, Wx_b, n1_ws, n2_ws, new_adj);
}